// Round 2
// baseline (10.967 us; speedup 1.0000x reference)
//
#include <hip/hip_runtime.h>

// Soft-DTW (banded, r1=BIG, R0 finite only at j=0) collapses exactly to the
// diagonal distance sum: out = sum_i sqrt(max(||x_i - y_i||^2, 1e-12)).
// Proof sketch: predecessors are (i-1,j-1) and (i-1,j) only, so j advances
// <=1 per step; R0 is finite only at j=0 and the readout is at j=T after T
// steps => unique contributing path j=i. Competing softmin branches at the
// diagonal are ~BIG=1e9, contributing exp(-2e9) == 0 exactly in f32/f64.

#define TN 4096
#define DFN 256
#define ROWS_PER_BLOCK 16
#define NBLK (TN / ROWS_PER_BLOCK)  // 256 partials

__global__ __launch_bounds__(256) void sdtw_diag(const float* __restrict__ x,
                                                 const float* __restrict__ y,
                                                 float* __restrict__ partial) {
  const int wave = threadIdx.x >> 6;  // 0..3
  const int lane = threadIdx.x & 63;
  __shared__ float wsum[4];

  float acc = 0.0f;
#pragma unroll
  for (int r = 0; r < 4; ++r) {
    const int row = blockIdx.x * ROWS_PER_BLOCK + wave * 4 + r;
    const float4 xv = reinterpret_cast<const float4*>(x)[row * (DFN / 4) + lane];
    const float4 yv = reinterpret_cast<const float4*>(y)[row * (DFN / 4) + lane];
    const float a = xv.x - yv.x;
    const float b = xv.y - yv.y;
    const float c = xv.z - yv.z;
    const float d = xv.w - yv.w;
    float d2 = a * a + b * b + c * c + d * d;
#pragma unroll
    for (int s = 32; s >= 1; s >>= 1) d2 += __shfl_xor(d2, s, 64);
    if (lane == 0) acc += sqrtf(fmaxf(d2, 1e-12f));
  }
  if (lane == 0) wsum[wave] = acc;
  __syncthreads();
  if (threadIdx.x == 0)
    partial[blockIdx.x] = (wsum[0] + wsum[1]) + (wsum[2] + wsum[3]);
}

__global__ __launch_bounds__(64) void sdtw_final(const float* __restrict__ partial,
                                                 float* __restrict__ out) {
  const int lane = threadIdx.x;
  float v = (partial[lane] + partial[lane + 64]) +
            (partial[lane + 128] + partial[lane + 192]);
#pragma unroll
  for (int s = 32; s >= 1; s >>= 1) v += __shfl_xor(v, s, 64);
  if (lane == 0) out[0] = v;
}

extern "C" void kernel_launch(void* const* d_in, const int* in_sizes, int n_in,
                              void* d_out, int out_size, void* d_ws,
                              size_t ws_size, hipStream_t stream) {
  const float* x = (const float*)d_in[0];
  const float* y = (const float*)d_in[1];
  float* partial = (float*)d_ws;  // NBLK floats = 1 KiB
  float* out = (float*)d_out;

  sdtw_diag<<<NBLK, 256, 0, stream>>>(x, y, partial);
  sdtw_final<<<1, 64, 0, stream>>>(partial, out);
}